// Round 3
// baseline (140.050 us; speedup 1.0000x reference)
//
#include <hip/hip_runtime.h>
#include <math.h>

#define B_ 4
#define N_ 512
#define D_ 64
#define NDIAG (2 * N_ - 1)   // 1023 diagonal rows of D
#define WV 4                 // waves per block
#define K_ 16                // diagonals per chunk (between barriers)
#define DC0 9                // chunk stagger between adjacent waves
#define NCH 40               // chunks per wave
#define CTOT (DC0 * (WV - 1) + NCH)  // 67
#define RING 1028            // non-wrapping ring: one slot per diagonal
#define BIGF 1e30f           // finite border sentinel: BIG + d rounds to BIG exactly

// Phase 1: D[b][i][j] = ||x[b,i,:]-y[b,j,:]||, stored diagonal-major
// ddiag[b][(i+j)][j] so phase 2 reads coalesce along anti-diagonals.
__global__ __launch_bounds__(256) void dist_diag_kernel(
    const float* __restrict__ x, const float* __restrict__ y,
    float* __restrict__ ddiag)
{
    const int b = blockIdx.z;
    const int i0 = blockIdx.y * 16;
    const int j0 = blockIdx.x * 16;
    __shared__ float xs[16 * 68];
    __shared__ float ys[16 * 68];
    const int t = threadIdx.x;
    const int lr = t >> 4;
    const int lc = t & 15;
    const float4* xsrc = (const float4*)(x + (((size_t)b * N_) + i0 + lr) * D_);
    const float4* ysrc = (const float4*)(y + (((size_t)b * N_) + j0 + lr) * D_);
    *(float4*)(&xs[lr * 68 + lc * 4]) = xsrc[lc];
    *(float4*)(&ys[lr * 68 + lc * 4]) = ysrc[lc];
    __syncthreads();

    const int ti = t >> 4, tj = t & 15;
    const float* xr = &xs[ti * 68];
    const float* yr = &ys[tj * 68];
    float acc = 0.f;
#pragma unroll
    for (int k = 0; k < 16; ++k) {
        float4 a = *(const float4*)(xr + 4 * k);
        float4 c = *(const float4*)(yr + 4 * k);
        float d0 = a.x - c.x, d1 = a.y - c.y, d2 = a.z - c.z, d3 = a.w - c.w;
        acc += d0 * d0 + d1 * d1 + d2 * d2 + d3 * d3;
    }
    const int i = i0 + ti, j = j0 + tj;
    ddiag[((size_t)b * NDIAG + (size_t)(i + j)) * N_ + j] = sqrtf(acc);
}

// whole-wave shift: lane l receives lane l-1 (DPP wave_shr:1)
__device__ __forceinline__ float dpp_shr1(float x) {
    int v = __builtin_amdgcn_update_dpp(0x7f800000, __float_as_int(x),
                                        0x138 /*WAVE_SHR1*/, 0xf, 0xf, false);
    return __int_as_float(v);
}

__device__ __forceinline__ float vmin3(float a, float b, float c) {
    float r; asm("v_min3_f32 %0, %1, %2, %3" : "=v"(r) : "v"(a), "v"(b), "v"(c)); return r;
}
__device__ __forceinline__ float vmed3(float a, float b, float c) {
    float r; asm("v_med3_f32 %0, %1, %2, %3" : "=v"(r) : "v"(a), "v"(b), "v"(c)); return r;
}
__device__ __forceinline__ float vmax3(float a, float b, float c) {
    float r; asm("v_max3_f32 %0, %1, %2, %3" : "=v"(r) : "v"(a), "v"(b), "v"(c)); return r;
}

#if __has_builtin(__builtin_amdgcn_exp2f)
#define EXP2(x) __builtin_amdgcn_exp2f(x)
#else
#define EXP2(x) exp2f(x)
#endif
#if __has_builtin(__builtin_amdgcn_logf)
#define LOG2(x) __builtin_amdgcn_logf(x)
#else
#define LOG2(x) log2f(x)
#endif

// Phase 2: staggered register-resident soft-DTW, mask-free (BIG sentinel),
// 3-transcendental softmin, one-chunk-deep dv double-buffer prefetch.
__global__ __launch_bounds__(256) void sdtw_stag2_kernel(
    const float* __restrict__ ddiag, float* __restrict__ out)
{
    const int b = blockIdx.x;
    const int tid = threadIdx.x;
    const int w = tid >> 6;
    const int lane = tid & 63;
    const float* Db = ddiag + (size_t)b * (NDIAG * (size_t)N_);

    // deterministic monotone paths: arange(512) for both
    for (int q = tid; q < N_; q += 256) {
        out[b * N_ + q] = (float)q;
        out[B_ * N_ + b * N_ + q] = (float)q;
    }

    // ring[w] = boundary column 128w (read by wave w, written by wave w-1).
    // ring[0] is the j=0 border: R[0][0]=0, R[i][0]=BIG. ring[WV] = dump row.
    __shared__ __align__(16) float ring[WV + 1][RING];
    for (int q = tid; q < (WV + 1) * RING; q += 256)
        (&ring[0][0])[q] = (q == 0) ? 0.0f : BIGF;
    __syncthreads();

    const float C1 = 14.4269504089f;    // (1/gamma)*log2(e)
    const float C2 = -0.069314718056f;  // -gamma*ln(2)
    const int jj0 = 128 * w + 2 * lane + 1;  // slot0 column (1-based)
    const int c0w = DC0 * w;
    const int s0w = 128 * w + 2;             // first diagonal for this wave
    const bool l0 = (lane == 0);
    const bool l63 = (lane == 63);
    const float* ringR = ring[w];
    float* ringW = ring[w + 1];

    // u0 = i0-1 (row index of slot0, minus 1), advances once per active step
    unsigned u0 = (unsigned)(-(2 * lane));
    float rA0 = BIGF, rB0 = BIGF, rA1 = BIGF;
    float lnL = BIGF, ldL = BIGF;
    float res = 0.0f;

    const float* dcol = Db + (jj0 - 1);
    float2 dvA[K_], dvB[K_];

    // prologue prefetch for wave 0 (other waves load at lc == -1)
    if (w == 0) {
#pragma unroll
        for (int t = 0; t < K_; ++t) {
            int row = s0w - 2 + t; if (row > NDIAG - 1) row = NDIAG - 1;
            dvA[t] = *(const float2*)(dcol + (size_t)row * N_);
        }
    }

    for (int c = 0; c < CTOT; ++c) {
        const int lc = c - c0w;
        if (lc >= 0 && lc < NCH) {
            const int s0c = s0w + lc * K_;
            // bulk ring read: slots s0c-2 .. s0c+15 (16B-aligned ds_read_b128)
            float rr[18];
            {
                const float4 q0 = *(const float4*)&ringR[s0c - 2];
                const float4 q1 = *(const float4*)&ringR[s0c + 2];
                const float4 q2 = *(const float4*)&ringR[s0c + 6];
                const float4 q3 = *(const float4*)&ringR[s0c + 10];
                const float2 q4 = *(const float2*)&ringR[s0c + 14];
                rr[0] = q0.x; rr[1] = q0.y; rr[2] = q0.z; rr[3] = q0.w;
                rr[4] = q1.x; rr[5] = q1.y; rr[6] = q1.z; rr[7] = q1.w;
                rr[8] = q2.x; rr[9] = q2.y; rr[10] = q2.z; rr[11] = q2.w;
                rr[12] = q3.x; rr[13] = q3.y; rr[14] = q3.z; rr[15] = q3.w;
                rr[16] = q4.x; rr[17] = q4.y;
            }
            // issue NEXT chunk's distance loads now: ~full chunk in flight
            if (lc + 1 < NCH) {
                const int s0n = s0c + K_;
#pragma unroll
                for (int t = 0; t < K_; ++t) {
                    int row = s0n - 2 + t; if (row > NDIAG - 1) row = NDIAG - 1;
                    dvB[t] = *(const float2*)(dcol + (size_t)row * N_);
                }
            }
            if (lc == 0) {  // prime left/diag for the very first step
                lnL = l0 ? rr[1] : BIGF;
                ldL = l0 ? rr[0] : BIGF;
            }
#pragma unroll
            for (int t = 0; t < K_; ++t) {
                const float d0 = dvA[t].x, d1 = dvA[t].y;
                // slot0: up=rA0, left=lnL, diag=ldL
                float m0  = vmin3(rA0, lnL, ldL);
                float md0 = vmed3(rA0, lnL, ldL);
                float mx0 = vmax3(rA0, lnL, ldL);
                float e0 = EXP2((m0 - md0) * C1);   // exact-0 arg when equal/BIG
                float f0 = EXP2((m0 - mx0) * C1);
                float r0 = fmaf(C2, LOG2(1.0f + e0 + f0), m0 + d0);
                // slot1: up=rA1, left=rA0(old), diag=rB0
                float m1  = vmin3(rA1, rA0, rB0);
                float md1 = vmed3(rA1, rA0, rB0);
                float mx1 = vmax3(rA1, rA0, rB0);
                float e1 = EXP2((m1 - md1) * C1);
                float f1 = EXP2((m1 - mx1) * C1);
                float r1 = fmaf(C2, LOG2(1.0f + e1 + f1), m1 + d1);
                // capture R[512][jj1] the step i1 hits 512 (before garbage)
                res = (u0 == 512u) ? r1 : res;
                u0 += 1u;
                rB0 = rA0; rA0 = r0;
                ldL = lnL;
                float sh = dpp_shr1(r1);
                lnL = l0 ? rr[t + 2] : sh;
                rA1 = r1;
                if (l63) ringW[s0c + t] = r1;       // boundary column out
            }
            // rotate prefetch buffer (vmcnt waited here, ~full chunk elapsed)
#pragma unroll
            for (int t = 0; t < K_; ++t) dvA[t] = dvB[t];
        } else if (lc == -1) {
            // one-interval-early prologue prefetch of this wave's chunk 0
#pragma unroll
            for (int t = 0; t < K_; ++t) {
                int row = s0w - 2 + t; if (row > NDIAG - 1) row = NDIAG - 1;
                dvA[t] = *(const float2*)(dcol + (size_t)row * N_);
            }
        }
        // LDS-only drain + barrier (keep dv global loads in flight)
        asm volatile("s_waitcnt lgkmcnt(0)" ::: "memory");
        __builtin_amdgcn_s_barrier();
    }

    // R[512][512] was captured by wave 3 / lane 63 at i1 == 512
    if (w == WV - 1 && l63) out[2 * B_ * N_ + b] = res;
}

extern "C" void kernel_launch(void* const* d_in, const int* in_sizes, int n_in,
                              void* d_out, int out_size, void* d_ws, size_t ws_size,
                              hipStream_t stream) {
    const float* x = (const float*)d_in[0];
    const float* y = (const float*)d_in[1];
    float* out = (float*)d_out;
    float* ddiag = (float*)d_ws;  // 4*1023*512*4 B = 8.0 MB

    dim3 g1(N_ / 16, N_ / 16, B_);
    dist_diag_kernel<<<g1, 256, 0, stream>>>(x, y, ddiag);
    sdtw_stag2_kernel<<<B_, 256, 0, stream>>>(ddiag, out);
}